// Round 3
// baseline (3959.829 us; speedup 1.0000x reference)
//
#include <hip/hip_runtime.h>
#include <stdint.h>
#include <math.h>

// Problem constants (B, H, T) = (16, 2048, 512)
#define Hdim   2048
#define Bdim   16
#define Tsteps 512
#define NWG    128   // workgroups; each owns KC columns of h
#define TPB    256   // 4 waves
#define KC     16    // h-columns per WG  (NWG*KC == Hdim)
#define NCHUNK 16    // K-chunks of 32 per wave (wave K-range = 512)

typedef __attribute__((ext_vector_type(8))) short short8_t;  // 8 bf16 (4 VGPRs)
typedef __attribute__((ext_vector_type(4))) float f32x4;     // MFMA C/D

// step-tag bit embedded in bit0 (low bf16 LSB) of every published h dword.
// tag(i) = ((i>>1)&1)^1 ; buffer slot = i&1  => (slot,tag) = i mod 4.
// Poison 0xAAAAAAAA has bit0==0; expected tag at steps 0,1 is 1 => no false match.
__device__ __forceinline__ uint32_t wantbit(int i) {
  return (uint32_t)((((unsigned)i >> 1) & 1u) ^ 1u);
}

__device__ __forceinline__ uint32_t f2bf_u(float x) {   // RNE, 16-bit result
  uint32_t u = __builtin_bit_cast(uint32_t, x);
  u += 0x7fffu + ((u >> 16) & 1u);
  return u >> 16;
}

// nearest bf16 whose LSB == w (error <= 1 ULP): trunc t; if parity matches take t,
// else t+1 (always the nearer candidate since frac in [0,1) ULP).
__device__ __forceinline__ uint32_t f2bf_lsb(float x, uint32_t w) {
  uint32_t t = __builtin_bit_cast(uint32_t, x) >> 16;
  return ((t & 1u) == w) ? t : t + 1u;
}

__device__ __forceinline__ short f2bf(float x) { return (short)f2bf_u(x); }

__device__ __forceinline__ short8_t load8_bf(const float* __restrict__ p) {
  short8_t r;
#pragma unroll
  for (int j = 0; j < 8; ++j) r[j] = f2bf(p[j]);
  return r;
}

__global__ void __launch_bounds__(TPB, 1) traj_kernel(
    const float* __restrict__ traj_z, const float* __restrict__ traj_input,
    const float* __restrict__ w_ih, const float* __restrict__ b_ih,
    const float* __restrict__ w_hh, const float* __restrict__ b_hh,
    const float* __restrict__ w_traj, const float* __restrict__ b_traj,
    float* __restrict__ out, uint32_t* __restrict__ hbuf32)
{
  const int tid  = threadIdx.x;
  const int wg   = blockIdx.x;
  const int wave = tid >> 6;
  const int lane = tid & 63;
  const int ln16 = lane & 15;       // MFMA: A row (batch) / B col / D col
  const int quad = lane >> 4;
  const int colbase = wg * KC;
  const int kwave   = wave * (Hdim / 4);   // this wave's K-quarter

  uint64_t* hbuf64 = (uint64_t*)hbuf32;

  __shared__ float s_red[4][3][16][16];  // wave, gate-tile, m(batch), n(col)
  __shared__ float s_x3[4][16];          // per-wave partial dot(h, w_traj)
  __shared__ float s_x[16];              // running x per batch

  // ---- preload w_hh slice as register-resident bf16 B-fragments ----
  short8_t wf0[NCHUNK], wf1[NCHUNK], wf2[NCHUNK], wt[NCHUNK];
#pragma unroll
  for (int c = 0; c < NCHUNK; ++c) {
    const int k0 = kwave + c * 32 + quad * 8;
    wf0[c] = load8_bf(w_hh + (size_t)(0 * Hdim + colbase + ln16) * Hdim + k0);
    wf1[c] = load8_bf(w_hh + (size_t)(1 * Hdim + colbase + ln16) * Hdim + k0);
    wf2[c] = load8_bf(w_hh + (size_t)(2 * Hdim + colbase + ln16) * Hdim + k0);
    short8_t g = {0, 0, 0, 0, 0, 0, 0, 0};
    if (ln16 == 0) g = load8_bf(w_traj + k0);
    wt[c] = g;
  }

  // ---- per-thread epilogue constants: thread (eb, ekc) owns h[eb][colbase+ekc] ----
  const int eb   = tid >> 4;
  const int ekc  = tid & 15;
  const int ecol = colbase + ekc;
  const float wr = w_ih[ecol], wz = w_ih[Hdim + ecol], wn = w_ih[2 * Hdim + ecol];
  const float br = b_ih[ecol] + b_hh[ecol];
  const float bz = b_ih[Hdim + ecol] + b_hh[Hdim + ecol];
  const float bin = b_ih[2 * Hdim + ecol];
  const float bhn = b_hh[2 * Hdim + ecol];
  const float bt  = b_traj[0];
  float h_own = traj_z[eb * Hdim + ecol];

  if (tid < 16) s_x[tid] = traj_input[tid * Tsteps];   // x0

  // ---- publish h_0 (tagged; agent-scope stores, no drain/flag needed) ----
  {
    const uint32_t w0 = wantbit(0);
    uint32_t rne = f2bf_u(h_own);
    uint32_t nb  = (uint32_t)__shfl_xor((int)rne, 1, 64);      // partner (odd lane) RNE
    uint32_t fo  = f2bf_lsb(h_own, w0);                        // own forced-LSB (even lane)
    if ((tid & 1) == 0) {
      uint32_t packed = (fo & 0xffffu) | (nb << 16);
      __hip_atomic_store(hbuf32 + ((eb * Hdim + ecol) >> 1),
                         packed, __ATOMIC_RELAXED, __HIP_MEMORY_SCOPE_AGENT);
    }
  }

  // step i: polls tagged h_i, computes h_{i+1} and x_i; out[:,i-1] = x_i.
  for (int i = 0; i <= Tsteps; ++i) {
    const uint32_t wb = wantbit(i);
    const uint64_t wp = (uint64_t)wb | ((uint64_t)wb << 32);
    const uint64_t* hrow = hbuf64 + (size_t)(i & 1) * (Bdim * Hdim / 4)
                         + ((ln16 * Hdim + kwave + quad * 8) >> 2);

    // poll the exact A-fragment words until every embedded tag matches step i
    union { uint64_t u[2]; short8_t s; } cv[NCHUNK];
    for (;;) {
      uint64_t bad = 0;
#pragma unroll
      for (int c = 0; c < NCHUNK; ++c) {
        cv[c].u[0] = __hip_atomic_load(hrow + c * 8,     __ATOMIC_RELAXED, __HIP_MEMORY_SCOPE_AGENT);
        cv[c].u[1] = __hip_atomic_load(hrow + c * 8 + 1, __ATOMIC_RELAXED, __HIP_MEMORY_SCOPE_AGENT);
      }
#pragma unroll
      for (int c = 0; c < NCHUNK; ++c) {
        bad |= (cv[c].u[0] ^ wp) & 0x0000000100000001ull;
        bad |= (cv[c].u[1] ^ wp) & 0x0000000100000001ull;
      }
      if (__ballot(bad != 0) == 0) break;
      __builtin_amdgcn_s_sleep(1);
    }

    f32x4 a0 = {0.f, 0.f, 0.f, 0.f}, a1 = a0, a2 = a0, a3 = a0;
#pragma unroll
    for (int c = 0; c < NCHUNK; ++c) {
      a0 = __builtin_amdgcn_mfma_f32_16x16x32_bf16(cv[c].s, wf0[c], a0, 0, 0, 0);
      a1 = __builtin_amdgcn_mfma_f32_16x16x32_bf16(cv[c].s, wf1[c], a1, 0, 0, 0);
      a2 = __builtin_amdgcn_mfma_f32_16x16x32_bf16(cv[c].s, wf2[c], a2, 0, 0, 0);
      a3 = __builtin_amdgcn_mfma_f32_16x16x32_bf16(cv[c].s, wt[c],  a3, 0, 0, 0);
    }

    // D[m][n]: n = lane&15, m = quad*4 + r
#pragma unroll
    for (int r = 0; r < 4; ++r) {
      const int m = quad * 4 + r;
      s_red[wave][0][m][ln16] = a0[r];
      s_red[wave][1][m][ln16] = a1[r];
      s_red[wave][2][m][ln16] = a2[r];
    }
    if (ln16 == 0) {
#pragma unroll
      for (int r = 0; r < 4; ++r) s_x3[wave][quad * 4 + r] = a3[r];
    }
    __syncthreads();

    if (tid < 16 && i > 0) {
      const float xd = s_x3[0][tid] + s_x3[1][tid] + s_x3[2][tid] + s_x3[3][tid];
      s_x[tid] += xd + bt;
    }
    __syncthreads();

    if (wg == 0 && tid < 16 && i > 0) out[tid * Tsteps + (i - 1)] = s_x[tid];
    if (i == Tsteps) break;

    // gates for (eb, ecol)
    const float gr = s_red[0][0][eb][ekc] + s_red[1][0][eb][ekc] + s_red[2][0][eb][ekc] + s_red[3][0][eb][ekc];
    const float gz = s_red[0][1][eb][ekc] + s_red[1][1][eb][ekc] + s_red[2][1][eb][ekc] + s_red[3][1][eb][ekc];
    const float gn = s_red[0][2][eb][ekc] + s_red[1][2][eb][ekc] + s_red[2][2][eb][ekc] + s_red[3][2][eb][ekc];
    const float x  = s_x[eb];
    const float rr = 1.f / (1.f + expf(-(x * wr + br + gr)));
    const float zz = 1.f / (1.f + expf(-(x * wz + bz + gz)));
    const float nn = tanhf(x * wn + bin + rr * (gn + bhn));
    h_own = (1.f - zz) * nn + zz * h_own;

    // publish h_{i+1} (tagged); no drain, no flag — consumers poll the data itself
    {
      const uint32_t w1 = wantbit(i + 1);
      uint32_t rne = f2bf_u(h_own);
      uint32_t nb  = (uint32_t)__shfl_xor((int)rne, 1, 64);
      uint32_t fo  = f2bf_lsb(h_own, w1);
      if ((tid & 1) == 0) {
        uint32_t packed = (fo & 0xffffu) | (nb << 16);
        __hip_atomic_store(hbuf32 + (size_t)((i + 1) & 1) * (Bdim * Hdim / 2)
                           + ((eb * Hdim + ecol) >> 1),
                           packed, __ATOMIC_RELAXED, __HIP_MEMORY_SCOPE_AGENT);
      }
    }
  }
}

extern "C" void kernel_launch(void* const* d_in, const int* in_sizes, int n_in,
                              void* d_out, int out_size, void* d_ws, size_t ws_size,
                              hipStream_t stream) {
  const float* traj_z     = (const float*)d_in[0];
  const float* traj_input = (const float*)d_in[1];
  const float* w_ih   = (const float*)d_in[2];
  const float* b_ih   = (const float*)d_in[3];
  const float* w_hh   = (const float*)d_in[4];
  const float* b_hh   = (const float*)d_in[5];
  const float* w_traj = (const float*)d_in[6];
  const float* b_traj = (const float*)d_in[7];
  float* out = (float*)d_out;

  // workspace poison 0xAA is REQUIRED semantics for the tag scheme (bit0==0).
  uint32_t* hbuf = (uint32_t*)d_ws;   // 2 * 16 * 2048 bf16 = 128 KB

  hipLaunchKernelGGL(traj_kernel, dim3(NWG), dim3(TPB), 0, stream,
                     traj_z, traj_input, w_ih, b_ih, w_hh, b_hh, w_traj, b_traj,
                     out, hbuf);
}

// Round 4
// 3529.268 us; speedup vs baseline: 1.1220x; 1.1220x over previous
//
#include <hip/hip_runtime.h>
#include <stdint.h>
#include <math.h>

// Problem constants (B, H, T) = (16, 2048, 512)
#define Hdim   2048
#define Bdim   16
#define Tsteps 512
#define NWG    128   // workgroups; each owns KC columns of h
#define TPB    256   // 4 waves
#define KC     16    // h-columns per WG  (NWG*KC == Hdim)
#define NCHUNK 16    // K-chunks of 32 per wave (wave K-range = 512)
#define NGRP   8     // flag groups; 16 WGs add into one counter
#define GSTRIDE 32   // dwords between group counters (128B lines)

typedef __attribute__((ext_vector_type(8))) short short8_t;  // 8 bf16 (4 VGPRs)
typedef __attribute__((ext_vector_type(4))) float f32x4;     // MFMA C/D

__device__ __forceinline__ short f2bf(float x) {
  uint32_t u = __builtin_bit_cast(uint32_t, x);
  u += 0x7fffu + ((u >> 16) & 1u);   // RNE
  return (short)(u >> 16);
}

__device__ __forceinline__ short8_t load8_bf(const float* __restrict__ p) {
  short8_t r;
#pragma unroll
  for (int j = 0; j < 8; ++j) r[j] = f2bf(p[j]);
  return r;
}

__global__ void __launch_bounds__(TPB, 1) traj_kernel(
    const float* __restrict__ traj_z, const float* __restrict__ traj_input,
    const float* __restrict__ w_ih, const float* __restrict__ b_ih,
    const float* __restrict__ w_hh, const float* __restrict__ b_hh,
    const float* __restrict__ w_traj, const float* __restrict__ b_traj,
    float* __restrict__ out, uint32_t* __restrict__ hbuf32, uint32_t* __restrict__ cnt)
{
  const int tid  = threadIdx.x;
  const int wg   = blockIdx.x;
  const int wave = tid >> 6;
  const int lane = tid & 63;
  const int ln16 = lane & 15;       // MFMA: A row (batch) / B col / D col
  const int quad = lane >> 4;
  const int colbase = wg * KC;
  const int kwave   = wave * (Hdim / 4);   // this wave's K-quarter

  uint64_t* hbuf64 = (uint64_t*)hbuf32;

  __shared__ float s_red[4][3][16][16];  // wave, gate-tile, m(batch), n(col)
  __shared__ float s_x3[4][16];          // per-wave partial dot(h, w_traj)

  // ---- preload w_hh slice as register-resident bf16 B-fragments ----
  // B[k][n]: n = lane&15 (tile row), k = quad*8 + j within each 32-chunk.
  short8_t wf0[NCHUNK], wf1[NCHUNK], wf2[NCHUNK], wt[NCHUNK];
#pragma unroll
  for (int c = 0; c < NCHUNK; ++c) {
    const int k0 = kwave + c * 32 + quad * 8;
    wf0[c] = load8_bf(w_hh + (size_t)(0 * Hdim + colbase + ln16) * Hdim + k0);
    wf1[c] = load8_bf(w_hh + (size_t)(1 * Hdim + colbase + ln16) * Hdim + k0);
    wf2[c] = load8_bf(w_hh + (size_t)(2 * Hdim + colbase + ln16) * Hdim + k0);
    short8_t g = {0, 0, 0, 0, 0, 0, 0, 0};
    if (ln16 == 0) g = load8_bf(w_traj + k0);
    wt[c] = g;
  }

  // ---- per-thread epilogue constants: thread (eb, ekc) owns h[eb][colbase+ekc] ----
  const int eb   = tid >> 4;
  const int ekc  = tid & 15;
  const int ecol = colbase + ekc;
  const float wr = w_ih[ecol], wz = w_ih[Hdim + ecol], wn = w_ih[2 * Hdim + ecol];
  const float br = b_ih[ecol] + b_hh[ecol];
  const float bz = b_ih[Hdim + ecol] + b_hh[Hdim + ecol];
  const float bin = b_ih[2 * Hdim + ecol];
  const float bhn = b_hh[2 * Hdim + ecol];
  const float bt  = b_traj[0];
  float h_own = traj_z[eb * Hdim + ecol];
  float x_run = traj_input[eb * Tsteps];     // running x for batch eb (same in all
                                             // threads sharing eb; updated identically)

  // ---- publish h_0 (agent-scope stores; pack 2 bf16 per dword) ----
  {
    uint32_t mybits = (uint32_t)(uint16_t)f2bf(h_own);
    uint32_t nb = (uint32_t)__shfl_xor((int)mybits, 1, 64);
    if ((tid & 1) == 0) {
      uint32_t packed = (mybits & 0xffffu) | (nb << 16);
      __hip_atomic_store(hbuf32 + ((eb * Hdim + ecol) >> 1),
                         packed, __ATOMIC_RELAXED, __HIP_MEMORY_SCOPE_AGENT);
    }
  }
  __syncthreads();   // drains vmcnt(0): h_0 stores acked at coherence point
  if (tid == 0)      // fire-and-forget group arrival
    __hip_atomic_fetch_add(cnt + (wg >> 4) * GSTRIDE, 1u,
                           __ATOMIC_RELAXED, __HIP_MEMORY_SCOPE_AGENT);

  // step i: waits for h_i (group counters), computes h_{i+1} and x_i;
  // out[:, i-1] = x_i. Extra iteration i==Tsteps computes only x_T.
  for (int i = 0; i <= Tsteps; ++i) {
    // ---- wait: all 8 group counters reached 16*(i+1) ----
    if (tid < NGRP) {
      const uint32_t want = 16u * (uint32_t)(i + 1);
      while (__hip_atomic_load(cnt + tid * GSTRIDE, __ATOMIC_RELAXED,
                               __HIP_MEMORY_SCOPE_AGENT) < want) {
        __builtin_amdgcn_s_sleep(1);
      }
    }
    __syncthreads();

    // ---- load A-fragments of h_i (agent-scope, bypass stale L1/L2) ----
    const uint64_t* hrow = hbuf64 + (size_t)(i & 1) * (Bdim * Hdim / 4)
                         + ((ln16 * Hdim + kwave + quad * 8) >> 2);
    short8_t af[NCHUNK];
#pragma unroll
    for (int c = 0; c < NCHUNK; ++c) {
      union { uint64_t u[2]; short8_t s; } cv;
      cv.u[0] = __hip_atomic_load(hrow + c * 8,     __ATOMIC_RELAXED, __HIP_MEMORY_SCOPE_AGENT);
      cv.u[1] = __hip_atomic_load(hrow + c * 8 + 1, __ATOMIC_RELAXED, __HIP_MEMORY_SCOPE_AGENT);
      af[c] = cv.s;
    }

    f32x4 a0 = {0.f, 0.f, 0.f, 0.f}, a1 = a0, a2 = a0, a3 = a0;
#pragma unroll
    for (int c = 0; c < NCHUNK; ++c) {
      a0 = __builtin_amdgcn_mfma_f32_16x16x32_bf16(af[c], wf0[c], a0, 0, 0, 0);
      a1 = __builtin_amdgcn_mfma_f32_16x16x32_bf16(af[c], wf1[c], a1, 0, 0, 0);
      a2 = __builtin_amdgcn_mfma_f32_16x16x32_bf16(af[c], wf2[c], a2, 0, 0, 0);
      a3 = __builtin_amdgcn_mfma_f32_16x16x32_bf16(af[c], wt[c],  a3, 0, 0, 0);
    }

    // D[m][n]: n = lane&15, m = quad*4 + r
#pragma unroll
    for (int r = 0; r < 4; ++r) {
      const int m = quad * 4 + r;
      s_red[wave][0][m][ln16] = a0[r];
      s_red[wave][1][m][ln16] = a1[r];
      s_red[wave][2][m][ln16] = a2[r];
    }
    if (ln16 == 0) {
#pragma unroll
      for (int r = 0; r < 4; ++r) s_x3[wave][quad * 4 + r] = a3[r];
    }
    __syncthreads();

    // x_i = x_{i-1} + dot(h_i, w_traj) + b_traj  (register-held, per-thread)
    if (i > 0)
      x_run += s_x3[0][eb] + s_x3[1][eb] + s_x3[2][eb] + s_x3[3][eb] + bt;
    if (wg == 0 && ekc == 0 && i > 0) out[eb * Tsteps + (i - 1)] = x_run;
    if (i == Tsteps) break;

    // gates for (eb, ecol)
    const float gr = s_red[0][0][eb][ekc] + s_red[1][0][eb][ekc] + s_red[2][0][eb][ekc] + s_red[3][0][eb][ekc];
    const float gz = s_red[0][1][eb][ekc] + s_red[1][1][eb][ekc] + s_red[2][1][eb][ekc] + s_red[3][1][eb][ekc];
    const float gn = s_red[0][2][eb][ekc] + s_red[1][2][eb][ekc] + s_red[2][2][eb][ekc] + s_red[3][2][eb][ekc];
    const float rr = 1.f / (1.f + expf(-(x_run * wr + br + gr)));
    const float zz = 1.f / (1.f + expf(-(x_run * wz + bz + gz)));
    const float nn = tanhf(x_run * wn + bin + rr * (gn + bhn));
    h_own = (1.f - zz) * nn + zz * h_own;

    // publish h_{i+1}
    {
      uint32_t mybits = (uint32_t)(uint16_t)f2bf(h_own);
      uint32_t nb = (uint32_t)__shfl_xor((int)mybits, 1, 64);
      if ((tid & 1) == 0) {
        uint32_t packed = (mybits & 0xffffu) | (nb << 16);
        __hip_atomic_store(hbuf32 + (size_t)((i + 1) & 1) * (Bdim * Hdim / 2)
                           + ((eb * Hdim + ecol) >> 1),
                           packed, __ATOMIC_RELAXED, __HIP_MEMORY_SCOPE_AGENT);
      }
    }
    __syncthreads();   // drain h stores (vmcnt(0)) before signalling arrival
    if (tid == 0)
      __hip_atomic_fetch_add(cnt + (wg >> 4) * GSTRIDE, 1u,
                             __ATOMIC_RELAXED, __HIP_MEMORY_SCOPE_AGENT);
  }
}

extern "C" void kernel_launch(void* const* d_in, const int* in_sizes, int n_in,
                              void* d_out, int out_size, void* d_ws, size_t ws_size,
                              hipStream_t stream) {
  const float* traj_z     = (const float*)d_in[0];
  const float* traj_input = (const float*)d_in[1];
  const float* w_ih   = (const float*)d_in[2];
  const float* b_ih   = (const float*)d_in[3];
  const float* w_hh   = (const float*)d_in[4];
  const float* b_hh   = (const float*)d_in[5];
  const float* w_traj = (const float*)d_in[6];
  const float* b_traj = (const float*)d_in[7];
  float* out = (float*)d_out;

  uint8_t*  ws   = (uint8_t*)d_ws;
  uint32_t* cnt  = (uint32_t*)ws;              // 8 counters, 128B apart (1 KB)
  uint32_t* hbuf = (uint32_t*)(ws + 1024);     // 2 * 16 * 2048 bf16 = 128 KB

  (void)hipMemsetAsync(cnt, 0, NGRP * GSTRIDE * 4, stream);  // counters start at 0
  hipLaunchKernelGGL(traj_kernel, dim3(NWG), dim3(TPB), 0, stream,
                     traj_z, traj_input, w_ih, b_ih, w_hh, b_hh, w_traj, b_traj,
                     out, hbuf, cnt);
}